// Round 1
// baseline (63.868 us; speedup 1.0000x reference)
//
#include <hip/hip_runtime.h>

// Problem constants (B=1)
#define H 8
#define S 4096
#define D 64          // D1 == D2 == 64
#define C 64          // chunk length
#define NC (S / C)    // 64 chunks per head

// ---------------------------------------------------------------------------
// Kernel 1: per-chunk local sums.
//   wsK [h][ch][64]       = sum over chunk of k_bar
//   wsKV[h][ch][64][64]   = sum over chunk of outer(k_bar, v)
// ---------------------------------------------------------------------------
__global__ __launch_bounds__(256) void k_chunk_sums(
    const float* __restrict__ k, const float* __restrict__ v,
    const float* __restrict__ coef_k,
    float* __restrict__ wsK, float* __restrict__ wsKV) {
  const int ch = blockIdx.x, h = blockIdx.y, t = threadIdx.x;
  __shared__ float kb[C][D + 1];
  __shared__ float vb[C][D + 1];

  const float* kp = k + (size_t)(h * S + ch * C) * D;
  const float* vp = v + (size_t)(h * S + ch * C) * D;
  const float* ck = coef_k + h * S + ch * C;

  for (int r = 0; r < 16; ++r) {
    int o = t + 256 * r;
    int i = o >> 6, d = o & 63;
    kb[i][d] = kp[o] * ck[i];
    vb[i][d] = vp[o];
  }
  __syncthreads();

  // sumK (threads 0..63): column sums of kb
  if (t < D) {
    float s = 0.f;
#pragma unroll
    for (int i = 0; i < C; ++i) s += kb[i][t];
    wsK[(h * NC + ch) * D + t] = s;
  }

  // sumKV: thread owns col c = t&63, rows a = 4r + (t>>6)
  const int w = t >> 6, c = t & 63;
  float acc[16];
#pragma unroll
  for (int r = 0; r < 16; ++r) acc[r] = 0.f;
  for (int i = 0; i < C; ++i) {
    float vic = vb[i][c];
#pragma unroll
    for (int r = 0; r < 16; ++r) acc[r] += kb[i][4 * r + w] * vic;
  }
  float* dst = wsKV + (size_t)(h * NC + ch) * (D * D);
#pragma unroll
  for (int r = 0; r < 16; ++r) dst[(4 * r + w) * D + c] = acc[r];
}

// ---------------------------------------------------------------------------
// Kernel 2: exclusive prefix scan across chunks (per head), in place.
// Elements of the 64+4096 state vector are independent chains.
// grid (4 segs, H); each thread owns 4 KV elements (ILP to hide latency).
// ---------------------------------------------------------------------------
__global__ __launch_bounds__(256) void k_scan(
    float* __restrict__ wsK, float* __restrict__ wsKV) {
  const int seg = blockIdx.x, h = blockIdx.y, t = threadIdx.x;
  const int e0 = seg * 1024 + t;
  float run[4] = {0.f, 0.f, 0.f, 0.f};
  for (int cc = 0; cc < NC; ++cc) {
    float* base = wsKV + (size_t)(h * NC + cc) * (D * D);
#pragma unroll
    for (int u = 0; u < 4; ++u) {
      float* p = base + e0 + 256 * u;
      float tmp = *p;
      *p = run[u];
      run[u] += tmp;
    }
  }
  if (seg == 0 && t < D) {
    float rk = 0.f;
    for (int cc = 0; cc < NC; ++cc) {
      float* p = wsK + (h * NC + cc) * D + t;
      float tmp = *p;
      *p = rk;
      rk += tmp;
    }
  }
}

// ---------------------------------------------------------------------------
// Kernel 3: per-chunk output.
//   A = tril(q_bar K_bar^T)  (inclusive)
//   P_i = max(|q_bar_i . T0 + rowsum_i(A)|, 1)
//   O_i = (q_bar_i S0 + (A V)_i) / P_i   -> RMSNorm over D2
// ---------------------------------------------------------------------------
__global__ __launch_bounds__(256) void k_chunk_out(
    const float* __restrict__ q, const float* __restrict__ k,
    const float* __restrict__ v,
    const float* __restrict__ coef_q, const float* __restrict__ coef_k,
    const float* __restrict__ mask_normer,
    const float* __restrict__ wsK, const float* __restrict__ wsKV,
    float* __restrict__ out) {
  const int ch = blockIdx.x, h = blockIdx.y, t = threadIdx.x;
  __shared__ float qb[C][D + 1];
  __shared__ float kv[C][D + 1];   // holds k_bar for A stage, then v
  __shared__ float S0[D][D + 1];
  __shared__ float A[C][C + 1];
  __shared__ float T0[D];
  __shared__ float P[C];

  const size_t base = (size_t)(h * S + ch * C) * D;
  const float* qp = q + base;
  const float* kp = k + base;
  const float* vp = v + base;
  const float* cq = coef_q + h * S + ch * C;
  const float* ck = coef_k + h * S + ch * C;
  const float* mn = mask_normer + h * S + ch * C;
  const float* t0p = wsK + (h * NC + ch) * D;
  const float* s0p = wsKV + (size_t)(h * NC + ch) * (D * D);

  for (int r = 0; r < 16; ++r) {
    int o = t + 256 * r;
    int i = o >> 6, d = o & 63;
    qb[i][d] = qp[o] * (cq[i] / mn[i]);
    kv[i][d] = kp[o] * ck[i];
    S0[i][d] = s0p[o];
  }
  if (t < D) T0[t] = t0p[t];
  __syncthreads();

  // P0_i = q_bar_i . T0   (threads 0..63; reads only pre-sync LDS)
  if (t < C) {
    float s = 0.f;
#pragma unroll
    for (int a = 0; a < D; ++a) s += qb[t][a] * T0[a];
    P[t] = s;
  }

  // A stage: thread owns col j = t&63, rows i = 4r + (t>>6)
  const int w = t >> 6, lane = t & 63;
  {
    float acc[16];
#pragma unroll
    for (int r = 0; r < 16; ++r) acc[r] = 0.f;
    for (int a = 0; a < D; ++a) {
      float kja = kv[lane][a];
#pragma unroll
      for (int r = 0; r < 16; ++r) acc[r] += qb[4 * r + w][a] * kja;
    }
#pragma unroll
    for (int r = 0; r < 16; ++r) {
      int i = 4 * r + w;
      A[i][lane] = (lane <= i) ? acc[r] : 0.f;
    }
  }
  __syncthreads();

  // overwrite kv with v; finalize P with row sums of A
  for (int r = 0; r < 16; ++r) {
    int o = t + 256 * r;
    int i = o >> 6, d = o & 63;
    kv[i][d] = vp[o];
  }
  if (t < C) {
    float rs = 0.f;
#pragma unroll
    for (int j = 0; j < C; ++j) rs += A[t][j];
    P[t] = fmaxf(fabsf(P[t] + rs), 1.0f);
  }
  __syncthreads();

  // O stage: thread owns col c = lane, rows i = 4r + w
  float acc[16];
#pragma unroll
  for (int r = 0; r < 16; ++r) acc[r] = 0.f;
  for (int a = 0; a < D; ++a) {
    float s0v = S0[a][lane];
#pragma unroll
    for (int r = 0; r < 16; ++r) acc[r] += qb[4 * r + w][a] * s0v;
  }
  for (int j = 0; j < C; ++j) {
    float vj = kv[j][lane];
#pragma unroll
    for (int r = 0; r < 16; ++r) acc[r] += A[4 * r + w][j] * vj;
  }

  float* op = out + base;
#pragma unroll
  for (int r = 0; r < 16; ++r) {
    int i = 4 * r + w;
    float val = acc[r] / P[i];
    // RMSNorm: row i spans exactly the 64 lanes of this wave
    float ss = val * val;
#pragma unroll
    for (int off = 32; off > 0; off >>= 1) ss += __shfl_xor(ss, off);
    float scale = rsqrtf(ss * (1.0f / D) + 1e-6f);
    op[i * D + lane] = val * scale;
  }
}

// ---------------------------------------------------------------------------
extern "C" void kernel_launch(void* const* d_in, const int* in_sizes, int n_in,
                              void* d_out, int out_size, void* d_ws, size_t ws_size,
                              hipStream_t stream) {
  (void)in_sizes; (void)n_in; (void)out_size; (void)ws_size;
  const float* q  = (const float*)d_in[0];
  const float* k  = (const float*)d_in[1];
  const float* v  = (const float*)d_in[2];
  const float* cq = (const float*)d_in[3];
  const float* ck = (const float*)d_in[4];
  const float* mn = (const float*)d_in[5];
  float* out = (float*)d_out;

  // workspace: wsK = H*NC*D floats (128 KiB), wsKV = H*NC*D*D floats (8 MiB)
  float* wsK  = (float*)d_ws;
  float* wsKV = wsK + (size_t)H * NC * D;

  dim3 blk(256);
  dim3 grd(NC, H);
  k_chunk_sums<<<grd, blk, 0, stream>>>(k, v, ck, wsK, wsKV);
  k_scan<<<dim3(4, H), blk, 0, stream>>>(wsK, wsKV);
  k_chunk_out<<<grd, blk, 0, stream>>>(q, k, v, cq, ck, mn, wsK, wsKV, out);
}

// Round 2
// 37.317 us; speedup vs baseline: 1.7115x; 1.7115x over previous
//
#include <hip/hip_runtime.h>

// Problem constants (B=1)
#define H 8
#define S 4096
#define D 64          // D1 == D2 == 64
#define C 64          // chunk length
#define NC (S / C)    // 64 chunks per head

struct alignas(16) F4 { float v[4]; };

// ---------------------------------------------------------------------------
// Kernel 1: per-chunk local sums (register-tiled, b128 LDS reads).
//   wsK [h][ch][64]     = sum over chunk of k_bar
//   wsKV[h][ch][64][64] = sum over chunk of outer(k_bar, v)
// ---------------------------------------------------------------------------
__global__ __launch_bounds__(256) void k_chunk_sums(
    const float* __restrict__ k, const float* __restrict__ v,
    const float* __restrict__ coef_k,
    float* __restrict__ wsK, float* __restrict__ wsKV) {
  const int ch = blockIdx.x, h = blockIdx.y, t = threadIdx.x;
  __shared__ float kb[C][D + 4];   // [i][a], row-major
  __shared__ float vb[C][D + 4];   // [i][c], row-major

  const float* kp = k + (size_t)(h * S + ch * C) * D;
  const float* vp = v + (size_t)(h * S + ch * C) * D;
  const float* ck = coef_k + h * S + ch * C;

#pragma unroll
  for (int r = 0; r < 4; ++r) {
    int o = 1024 * r + 4 * t;
    int i = o >> 6, d = o & 63;
    F4 kv = *reinterpret_cast<const F4*>(kp + o);
    F4 vv = *reinterpret_cast<const F4*>(vp + o);
    float c = ck[i];
#pragma unroll
    for (int u = 0; u < 4; ++u) kv.v[u] *= c;
    *reinterpret_cast<F4*>(&kb[i][d]) = kv;
    *reinterpret_cast<F4*>(&vb[i][d]) = vv;
  }
  __syncthreads();

  // column sums of k_bar -> wsK
  if (t < D) {
    float s = 0.f;
#pragma unroll
    for (int i = 0; i < C; ++i) s += kb[i][t];
    wsK[(h * NC + ch) * D + t] = s;
  }

  // outer-product sum: thread (ta,tc) owns 4x4 tile (a,c)
  const int ta = t >> 4, tc = t & 15;
  float acc[4][4];
#pragma unroll
  for (int a = 0; a < 4; ++a)
#pragma unroll
    for (int b = 0; b < 4; ++b) acc[a][b] = 0.f;

  for (int i = 0; i < C; ++i) {
    F4 ka = *reinterpret_cast<const F4*>(&kb[i][4 * ta]);
    F4 vc = *reinterpret_cast<const F4*>(&vb[i][4 * tc]);
#pragma unroll
    for (int a = 0; a < 4; ++a)
#pragma unroll
      for (int b = 0; b < 4; ++b) acc[a][b] += ka.v[a] * vc.v[b];
  }
  float* dst = wsKV + (size_t)(h * NC + ch) * (D * D);
#pragma unroll
  for (int a = 0; a < 4; ++a) {
    F4 w;
#pragma unroll
    for (int b = 0; b < 4; ++b) w.v[b] = acc[a][b];
    *reinterpret_cast<F4*>(dst + (4 * ta + a) * D + 4 * tc) = w;
  }
}

// ---------------------------------------------------------------------------
// Kernel 2: exclusive prefix scan across chunks (per head), in place.
// grid (32, H) x 128 threads: each thread owns 1 of the 4096 KV elements,
// 8-deep load batching to keep HBM latency off the critical path.
// ---------------------------------------------------------------------------
__global__ __launch_bounds__(128) void k_scan(
    float* __restrict__ wsK, float* __restrict__ wsKV) {
  const int seg = blockIdx.x, h = blockIdx.y, t = threadIdx.x;
  const int e0 = seg * 128 + t;
  float run = 0.f;
  for (int base = 0; base < NC; base += 8) {
    float x[8];
#pragma unroll
    for (int u = 0; u < 8; ++u)
      x[u] = wsKV[(size_t)(h * NC + base + u) * (D * D) + e0];
#pragma unroll
    for (int u = 0; u < 8; ++u) {
      wsKV[(size_t)(h * NC + base + u) * (D * D) + e0] = run;
      run += x[u];
    }
  }
  // wsK scan: fully register-resident (64 independent loads, then stores)
  if (seg == 0 && t < D) {
    float vals[NC];
#pragma unroll
    for (int cc = 0; cc < NC; ++cc) vals[cc] = wsK[(h * NC + cc) * D + t];
    float rk = 0.f;
#pragma unroll
    for (int cc = 0; cc < NC; ++cc) {
      wsK[(h * NC + cc) * D + t] = rk;
      rk += vals[cc];
    }
  }
}

// ---------------------------------------------------------------------------
// Kernel 3: per-chunk output (register-tiled 4x4, all LDS reads b128).
//   A = tril(q_bar K_bar^T) ;  P_i = max(|q_bar_i.T0 + rowsum_i(A)|, 1)
//   O_i = (q_bar_i S0 + (A V)_i) / P_i  -> RMSNorm over D2
// ---------------------------------------------------------------------------
__global__ __launch_bounds__(256) void k_chunk_out(
    const float* __restrict__ q, const float* __restrict__ k,
    const float* __restrict__ v,
    const float* __restrict__ coef_q, const float* __restrict__ coef_k,
    const float* __restrict__ mask_normer,
    const float* __restrict__ wsK, const float* __restrict__ wsKV,
    float* __restrict__ out) {
  const int ch = blockIdx.x, h = blockIdx.y, t = threadIdx.x;
  __shared__ float qbT[D][C + 4];  // [a][i]  (transposed)
  __shared__ float kvb[D][C + 4];  // k_bar transposed [a][j]; later v row-major [j][c]
  __shared__ float S0[D][D + 4];   // [a][c]  row-major
  __shared__ float AT[C][C + 4];   // [j][i]  (A transposed)
  __shared__ float T0[D];
  __shared__ float P0[C];
  __shared__ float PR[C];
  __shared__ float P[C];

  const size_t base = (size_t)(h * S + ch * C) * D;
  const float* qp = q + base;
  const float* kp = k + base;
  const float* vp = v + base;
  const float* cq = coef_q + h * S + ch * C;
  const float* ck = coef_k + h * S + ch * C;
  const float* mn = mask_normer + h * S + ch * C;
  const float* t0p = wsK + (h * NC + ch) * D;
  const float* s0p = wsKV + (size_t)(h * NC + ch) * (D * D);

#pragma unroll
  for (int r = 0; r < 4; ++r) {
    int o = 1024 * r + 4 * t;
    int i = o >> 6, d = o & 63;
    F4 qv = *reinterpret_cast<const F4*>(qp + o);
    F4 kv = *reinterpret_cast<const F4*>(kp + o);
    F4 s0 = *reinterpret_cast<const F4*>(s0p + o);
    float sq = cq[i] / mn[i];
    float sk = ck[i];
#pragma unroll
    for (int u = 0; u < 4; ++u) {
      qbT[d + u][i] = qv.v[u] * sq;
      kvb[d + u][i] = kv.v[u] * sk;
    }
    *reinterpret_cast<F4*>(&S0[i][d]) = s0;
  }
  if (t < D) T0[t] = t0p[t];
  __syncthreads();

  // P0_i = q_bar_i . T0
  if (t < C) {
    float s = 0.f;
#pragma unroll
    for (int a = 0; a < D; ++a) s += qbT[a][t] * T0[a];
    P0[t] = s;
  }

  const int ti = t >> 4, tj = t & 15;   // tile row-group, col-group

  // A stage: thread owns rows 4ti.., cols 4tj..
  {
    float acc[4][4];
#pragma unroll
    for (int a = 0; a < 4; ++a)
#pragma unroll
      for (int b = 0; b < 4; ++b) acc[a][b] = 0.f;
    for (int a = 0; a < D; ++a) {
      F4 qv = *reinterpret_cast<const F4*>(&qbT[a][4 * ti]);
      F4 kv = *reinterpret_cast<const F4*>(&kvb[a][4 * tj]);
#pragma unroll
      for (int ii = 0; ii < 4; ++ii)
#pragma unroll
        for (int jj = 0; jj < 4; ++jj) acc[ii][jj] += qv.v[ii] * kv.v[jj];
    }
    // causal mask + row-sum partials
    float rs[4];
#pragma unroll
    for (int ii = 0; ii < 4; ++ii) {
      int i = 4 * ti + ii;
      float r = 0.f;
#pragma unroll
      for (int jj = 0; jj < 4; ++jj) {
        int j = 4 * tj + jj;
        float m = (j <= i) ? acc[ii][jj] : 0.f;
        acc[ii][jj] = m;
        r += m;
      }
      rs[ii] = r;
    }
#pragma unroll
    for (int off = 1; off < 16; off <<= 1)
#pragma unroll
      for (int ii = 0; ii < 4; ++ii) rs[ii] += __shfl_xor(rs[ii], off);
    if (tj == 0) {
#pragma unroll
      for (int ii = 0; ii < 4; ++ii) PR[4 * ti + ii] = rs[ii];
    }
    // store A transposed: AT[j][i]
#pragma unroll
    for (int jj = 0; jj < 4; ++jj) {
      F4 w;
#pragma unroll
      for (int ii = 0; ii < 4; ++ii) w.v[ii] = acc[ii][jj];
      *reinterpret_cast<F4*>(&AT[4 * tj + jj][4 * ti]) = w;
    }
  }
  __syncthreads();

  // overwrite kvb with v (row-major); finalize P
#pragma unroll
  for (int r = 0; r < 4; ++r) {
    int o = 1024 * r + 4 * t;
    int i = o >> 6, d = o & 63;
    F4 vv = *reinterpret_cast<const F4*>(vp + o);
    *reinterpret_cast<F4*>(&kvb[i][d]) = vv;
  }
  if (t < C) P[t] = fmaxf(fabsf(P0[t] + PR[t]), 1.0f);
  __syncthreads();

  // O stage: thread owns rows 4ti.., out-cols 4tj..
  float oacc[4][4];
#pragma unroll
  for (int a = 0; a < 4; ++a)
#pragma unroll
    for (int b = 0; b < 4; ++b) oacc[a][b] = 0.f;
  for (int a = 0; a < D; ++a) {
    F4 qv = *reinterpret_cast<const F4*>(&qbT[a][4 * ti]);
    F4 s0 = *reinterpret_cast<const F4*>(&S0[a][4 * tj]);
#pragma unroll
    for (int ii = 0; ii < 4; ++ii)
#pragma unroll
      for (int cc = 0; cc < 4; ++cc) oacc[ii][cc] += qv.v[ii] * s0.v[cc];
  }
  for (int j = 0; j < C; ++j) {
    F4 av = *reinterpret_cast<const F4*>(&AT[j][4 * ti]);
    F4 vv = *reinterpret_cast<const F4*>(&kvb[j][4 * tj]);
#pragma unroll
    for (int ii = 0; ii < 4; ++ii)
#pragma unroll
      for (int cc = 0; cc < 4; ++cc) oacc[ii][cc] += av.v[ii] * vv.v[cc];
  }

  // epilogue: divide by P, RMSNorm per row (row spans 16 lanes, same wave)
  float* op = out + base;
#pragma unroll
  for (int ii = 0; ii < 4; ++ii) {
    int i = 4 * ti + ii;
    float pinv = 1.0f / P[i];
    float vals[4];
    float ss = 0.f;
#pragma unroll
    for (int cc = 0; cc < 4; ++cc) {
      float x = oacc[ii][cc] * pinv;
      vals[cc] = x;
      ss += x * x;
    }
#pragma unroll
    for (int off = 1; off < 16; off <<= 1) ss += __shfl_xor(ss, off);
    float scale = rsqrtf(ss * (1.0f / D) + 1e-6f);
    F4 w;
#pragma unroll
    for (int cc = 0; cc < 4; ++cc) w.v[cc] = vals[cc] * scale;
    *reinterpret_cast<F4*>(op + (size_t)i * D + 4 * tj) = w;
  }
}

// ---------------------------------------------------------------------------
extern "C" void kernel_launch(void* const* d_in, const int* in_sizes, int n_in,
                              void* d_out, int out_size, void* d_ws, size_t ws_size,
                              hipStream_t stream) {
  (void)in_sizes; (void)n_in; (void)out_size; (void)ws_size;
  const float* q  = (const float*)d_in[0];
  const float* k  = (const float*)d_in[1];
  const float* v  = (const float*)d_in[2];
  const float* cq = (const float*)d_in[3];
  const float* ck = (const float*)d_in[4];
  const float* mn = (const float*)d_in[5];
  float* out = (float*)d_out;

  float* wsK  = (float*)d_ws;                      // H*NC*D floats
  float* wsKV = wsK + (size_t)H * NC * D;          // H*NC*D*D floats

  k_chunk_sums<<<dim3(NC, H), dim3(256), 0, stream>>>(k, v, ck, wsK, wsKV);
  k_scan<<<dim3(32, H), dim3(128), 0, stream>>>(wsK, wsKV);
  k_chunk_out<<<dim3(NC, H), dim3(256), 0, stream>>>(q, k, v, cq, ck, mn, wsK, wsKV, out);
}

// Round 3
// 27.891 us; speedup vs baseline: 2.2899x; 1.3379x over previous
//
#include <hip/hip_runtime.h>

// Problem constants (B=1)
#define H 8
#define S 4096
#define D 64          // D1 == D2 == 64
#define C 64          // chunk length
#define NC (S / C)    // 64 chunks per head
#define PITCH 72      // bf16 LDS row pitch (144B = 16B-aligned, 4-bank rotation)

typedef short bf16x8 __attribute__((ext_vector_type(8)));
typedef float f32x4 __attribute__((ext_vector_type(4)));

struct alignas(16) F4 { float v[4]; };

__device__ inline short rne_bf16(float x) {
  unsigned u = __builtin_bit_cast(unsigned, x);
  unsigned r = u + 0x7fffu + ((u >> 16) & 1u);
  return (short)(r >> 16);
}
__device__ inline float bf16_to_f(short h) {
  unsigned u = ((unsigned)(unsigned short)h) << 16;
  return __builtin_bit_cast(float, u);
}

// ---------------------------------------------------------------------------
// Kernel 1: per-chunk local state, stored TRANSPOSED: wsKV[h][ch][c][a] =
//   sum over chunk of v[i][c] * k_bar[i][a]   (f32, for scan precision)
// ---------------------------------------------------------------------------
__global__ __launch_bounds__(256) void k_chunk_sums(
    const float* __restrict__ k, const float* __restrict__ v,
    const float* __restrict__ coef_k, float* __restrict__ wsKV) {
  const int ch = blockIdx.x, h = blockIdx.y, t = threadIdx.x;
  __shared__ float kb[C][D + 4];
  __shared__ float vb[C][D + 4];

  const float* kp = k + (size_t)(h * S + ch * C) * D;
  const float* vp = v + (size_t)(h * S + ch * C) * D;
  const float* ck = coef_k + h * S + ch * C;

#pragma unroll
  for (int r = 0; r < 4; ++r) {
    int o = 1024 * r + 4 * t;
    int i = o >> 6, d = o & 63;
    F4 kv = *reinterpret_cast<const F4*>(kp + o);
    F4 vv = *reinterpret_cast<const F4*>(vp + o);
    float c = ck[i];
#pragma unroll
    for (int u = 0; u < 4; ++u) kv.v[u] *= c;
    *reinterpret_cast<F4*>(&kb[i][d]) = kv;
    *reinterpret_cast<F4*>(&vb[i][d]) = vv;
  }
  __syncthreads();

  // thread (tc,ta) owns 4x4 tile of state_T[c][a]
  const int tc = t >> 4, ta = t & 15;
  float acc[4][4];
#pragma unroll
  for (int a = 0; a < 4; ++a)
#pragma unroll
    for (int b = 0; b < 4; ++b) acc[a][b] = 0.f;

  for (int i = 0; i < C; ++i) {
    F4 vc = *reinterpret_cast<const F4*>(&vb[i][4 * tc]);
    F4 ka = *reinterpret_cast<const F4*>(&kb[i][4 * ta]);
#pragma unroll
    for (int cc = 0; cc < 4; ++cc)
#pragma unroll
      for (int aa = 0; aa < 4; ++aa) acc[cc][aa] += vc.v[cc] * ka.v[aa];
  }
  float* dst = wsKV + (size_t)(h * NC + ch) * (D * D);
#pragma unroll
  for (int cc = 0; cc < 4; ++cc) {
    F4 w;
#pragma unroll
    for (int aa = 0; aa < 4; ++aa) w.v[aa] = acc[cc][aa];
    *reinterpret_cast<F4*>(dst + (4 * tc + cc) * D + 4 * ta) = w;
  }
}

// ---------------------------------------------------------------------------
// Kernel 2: exclusive prefix scan across chunks (per head), writing each
// prefix back IN PLACE as packed {bf16 hi, bf16 lo} (hi in low half).
// ---------------------------------------------------------------------------
__global__ __launch_bounds__(128) void k_scan(float* __restrict__ wsKV) {
  const int seg = blockIdx.x, h = blockIdx.y, t = threadIdx.x;
  const int e0 = seg * 128 + t;
  unsigned* wp = reinterpret_cast<unsigned*>(wsKV);
  float run = 0.f;
  for (int base = 0; base < NC; base += 8) {
    float x[8];
#pragma unroll
    for (int u = 0; u < 8; ++u)
      x[u] = wsKV[(size_t)(h * NC + base + u) * (D * D) + e0];
#pragma unroll
    for (int u = 0; u < 8; ++u) {
      short hi = rne_bf16(run);
      short lo = rne_bf16(run - bf16_to_f(hi));
      wp[(size_t)(h * NC + base + u) * (D * D) + e0] =
          (((unsigned)(unsigned short)lo) << 16) | (unsigned)(unsigned short)hi;
      run += x[u];
    }
  }
}

// ---------------------------------------------------------------------------
// Kernel 3: per-chunk output via MFMA 16x16x32 bf16.
//   A = tril(q_bar K_bar^T);  O = q_bar*(S0hi+S0lo) + A*V;  rmsnorm(O).
//   (P normalizer dropped: rmsnorm makes it a 1e-6-level perturbation.)
// LDS layouts are K-contiguous: A-ops [M][K], B-ops [N][K], pitch 72 shorts.
// ---------------------------------------------------------------------------
__global__ __launch_bounds__(256) void k_chunk_out(
    const float* __restrict__ q, const float* __restrict__ k,
    const float* __restrict__ v,
    const float* __restrict__ coef_q, const float* __restrict__ coef_k,
    const float* __restrict__ mask_normer,
    const float* __restrict__ wsKV, float* __restrict__ out) {
  const int ch = blockIdx.x, h = blockIdx.y, t = threadIdx.x;
  __shared__ alignas(16) short qb[C * PITCH];    // q_bar  [i][a]
  __shared__ alignas(16) short kbf[C * PITCH];   // k_bar  [j][a]
  __shared__ alignas(16) short s0h[D * PITCH];   // S0 hi  [c][a]
  __shared__ alignas(16) short s0l[D * PITCH];   // S0 lo  [c][a]
  __shared__ alignas(16) short vT[D * PITCH];    // v^T    [c][j]
  __shared__ alignas(16) short Ab[C * PITCH];    // A      [i][j] (wave-private rows)

  const size_t base = (size_t)(h * S + ch * C) * D;
  const float* qp = q + base;
  const float* kp = k + base;
  const float* cq = coef_q + h * S + ch * C;
  const float* ck = coef_k + h * S + ch * C;
  const float* mn = mask_normer + h * S + ch * C;
  const unsigned* s0p =
      reinterpret_cast<const unsigned*>(wsKV) + (size_t)(h * NC + ch) * (D * D);

  // ---- staging: thread t handles 16 contiguous elements (row t>>2, col16 t&3)
  {
    const int i = t >> 2, c0 = (t & 3) * 16;
    const float sq = cq[i] / mn[i];
    const float sk = ck[i];
    bf16x8 wq[2], wk[2], wh[2], wl[2];
#pragma unroll
    for (int g = 0; g < 2; ++g) {
#pragma unroll
      for (int u0 = 0; u0 < 8; u0 += 4) {
        F4 qv = *reinterpret_cast<const F4*>(qp + i * D + c0 + 8 * g + u0);
        F4 kv = *reinterpret_cast<const F4*>(kp + i * D + c0 + 8 * g + u0);
#pragma unroll
        for (int u = 0; u < 4; ++u) {
          wq[g][u0 + u] = rne_bf16(qv.v[u] * sq);
          wk[g][u0 + u] = rne_bf16(kv.v[u] * sk);
        }
      }
      // packed S0 prefix (hi low-half, lo high-half)
#pragma unroll
      for (int u = 0; u < 8; ++u) {
        unsigned p = s0p[i * D + c0 + 8 * g + u];
        wh[g][u] = (short)(p & 0xffffu);
        wl[g][u] = (short)(p >> 16);
      }
    }
#pragma unroll
    for (int g = 0; g < 2; ++g) {
      *reinterpret_cast<bf16x8*>(&qb[i * PITCH + c0 + 8 * g]) = wq[g];
      *reinterpret_cast<bf16x8*>(&kbf[i * PITCH + c0 + 8 * g]) = wk[g];
      *reinterpret_cast<bf16x8*>(&s0h[i * PITCH + c0 + 8 * g]) = wh[g];
      *reinterpret_cast<bf16x8*>(&s0l[i * PITCH + c0 + 8 * g]) = wl[g];
    }
  }
  // ---- vT staging: thread t builds vT[c][i0..i0+15] from global columns
  {
    const int c = t >> 2, i0 = (t & 3) * 16;
    const float* vcol = v + base + c;
    bf16x8 wv[2];
#pragma unroll
    for (int g = 0; g < 2; ++g)
#pragma unroll
      for (int u = 0; u < 8; ++u)
        wv[g][u] = rne_bf16(vcol[(size_t)(i0 + 8 * g + u) * D]);
    *reinterpret_cast<bf16x8*>(&vT[c * PITCH + i0]) = wv[0];
    *reinterpret_cast<bf16x8*>(&vT[c * PITCH + i0 + 8]) = wv[1];
  }
  __syncthreads();

  const int lane = t & 63, w = t >> 6;
  const int arow = lane & 15, kg = lane >> 4;
  const int rbase = (16 * w + arow) * PITCH + 8 * kg;

  // q A-fragments (reused across all stages)
  bf16x8 qa0 = *reinterpret_cast<const bf16x8*>(&qb[rbase]);
  bf16x8 qa1 = *reinterpret_cast<const bf16x8*>(&qb[rbase + 32]);

  // ---- A-stage: wave w computes rows 16w..16w+15, all 4 col-tiles
  f32x4 accA[4];
#pragma unroll
  for (int n = 0; n < 4; ++n) {
    const int bb = (16 * n + arow) * PITCH + 8 * kg;
    bf16x8 b0 = *reinterpret_cast<const bf16x8*>(&kbf[bb]);
    bf16x8 b1 = *reinterpret_cast<const bf16x8*>(&kbf[bb + 32]);
    f32x4 z = {0.f, 0.f, 0.f, 0.f};
    z = __builtin_amdgcn_mfma_f32_16x16x32_bf16(qa0, b0, z, 0, 0, 0);
    z = __builtin_amdgcn_mfma_f32_16x16x32_bf16(qa1, b1, z, 0, 0, 0);
    accA[n] = z;
  }
  // causal mask + bf16 A into LDS (rows 16w.. are wave-private)
#pragma unroll
  for (int n = 0; n < 4; ++n)
#pragma unroll
    for (int r = 0; r < 4; ++r) {
      int i = 4 * kg + r;         // local row in stripe
      int j = 16 * n + arow;      // local col in chunk
      float x = (j <= 16 * w + i) ? accA[n][r] : 0.f;
      Ab[(16 * w + i) * PITCH + j] = rne_bf16(x);
    }

  // ---- O-stage (same-wave LDS read-after-write; compiler inserts lgkmcnt)
  bf16x8 aa0 = *reinterpret_cast<const bf16x8*>(&Ab[rbase]);
  bf16x8 aa1 = *reinterpret_cast<const bf16x8*>(&Ab[rbase + 32]);
  f32x4 accO[4];
#pragma unroll
  for (int n = 0; n < 4; ++n) {
    const int bb = (16 * n + arow) * PITCH + 8 * kg;
    bf16x8 h0 = *reinterpret_cast<const bf16x8*>(&s0h[bb]);
    bf16x8 h1 = *reinterpret_cast<const bf16x8*>(&s0h[bb + 32]);
    bf16x8 l0 = *reinterpret_cast<const bf16x8*>(&s0l[bb]);
    bf16x8 l1 = *reinterpret_cast<const bf16x8*>(&s0l[bb + 32]);
    bf16x8 v0 = *reinterpret_cast<const bf16x8*>(&vT[bb]);
    bf16x8 v1 = *reinterpret_cast<const bf16x8*>(&vT[bb + 32]);
    f32x4 z = {0.f, 0.f, 0.f, 0.f};
    z = __builtin_amdgcn_mfma_f32_16x16x32_bf16(qa0, h0, z, 0, 0, 0);
    z = __builtin_amdgcn_mfma_f32_16x16x32_bf16(qa1, h1, z, 0, 0, 0);
    z = __builtin_amdgcn_mfma_f32_16x16x32_bf16(qa0, l0, z, 0, 0, 0);
    z = __builtin_amdgcn_mfma_f32_16x16x32_bf16(qa1, l1, z, 0, 0, 0);
    z = __builtin_amdgcn_mfma_f32_16x16x32_bf16(aa0, v0, z, 0, 0, 0);
    z = __builtin_amdgcn_mfma_f32_16x16x32_bf16(aa1, v1, z, 0, 0, 0);
    accO[n] = z;
  }

  // ---- epilogue: rmsnorm per row (row lives in one quarter-wave)
  float* op = out + base;
#pragma unroll
  for (int r = 0; r < 4; ++r) {
    const int i = 16 * w + 4 * kg + r;
    float ss = 0.f;
#pragma unroll
    for (int n = 0; n < 4; ++n) ss += accO[n][r] * accO[n][r];
#pragma unroll
    for (int off = 1; off < 16; off <<= 1) ss += __shfl_xor(ss, off);
    const float sc = rsqrtf(ss * (1.0f / D) + 1e-6f);
#pragma unroll
    for (int n = 0; n < 4; ++n)
      op[(size_t)i * D + 16 * n + arow] = accO[n][r] * sc;
  }
}

// ---------------------------------------------------------------------------
extern "C" void kernel_launch(void* const* d_in, const int* in_sizes, int n_in,
                              void* d_out, int out_size, void* d_ws, size_t ws_size,
                              hipStream_t stream) {
  (void)in_sizes; (void)n_in; (void)out_size; (void)ws_size;
  const float* q  = (const float*)d_in[0];
  const float* k  = (const float*)d_in[1];
  const float* v  = (const float*)d_in[2];
  const float* cq = (const float*)d_in[3];
  const float* ck = (const float*)d_in[4];
  const float* mn = (const float*)d_in[5];
  float* out = (float*)d_out;

  float* wsKV = (float*)d_ws;   // H*NC*D*D floats (8 MiB), packed in place by k_scan

  k_chunk_sums<<<dim3(NC, H), dim3(256), 0, stream>>>(k, v, ck, wsKV);
  k_scan<<<dim3(32, H), dim3(128), 0, stream>>>(wsKV);
  k_chunk_out<<<dim3(NC, H), dim3(256), 0, stream>>>(q, k, v, cq, ck, mn, wsKV, out);
}

// Round 4
// 25.623 us; speedup vs baseline: 2.4926x; 1.0885x over previous
//
#include <hip/hip_runtime.h>

// Problem constants (B=1)
#define H 8
#define S 4096
#define D 64          // D1 == D2 == 64
#define C 64          // chunk length
#define NC (S / C)    // 64 chunks per head
#define PITCH 72      // bf16 LDS row pitch (144B, 16B-aligned, 4-bank rotation)
#define FP 68         // f32 staging pitch (272B, 16B-aligned)

typedef short bf16x8 __attribute__((ext_vector_type(8)));
typedef float f32x4 __attribute__((ext_vector_type(4)));
typedef unsigned uint4v __attribute__((ext_vector_type(4)));

struct alignas(16) F4 { float v[4]; };

__device__ inline short rne_bf16(float x) {
  unsigned u = __builtin_bit_cast(unsigned, x);
  unsigned r = u + 0x7fffu + ((u >> 16) & 1u);
  return (short)(r >> 16);
}
__device__ inline float bf16_to_f(short h) {
  unsigned u = ((unsigned)(unsigned short)h) << 16;
  return __builtin_bit_cast(float, u);
}

// ---------------------------------------------------------------------------
// Kernel 1: per-chunk local state via MFMA, stored TRANSPOSED (f32):
//   wsKV[h][ch][c][a] = sum over chunk of v[i][c] * k_bar[i][a]
// ---------------------------------------------------------------------------
__global__ __launch_bounds__(256) void k_chunk_sums(
    const float* __restrict__ k, const float* __restrict__ v,
    const float* __restrict__ coef_k, float* __restrict__ wsKV) {
  const int ch = blockIdx.x, h = blockIdx.y, t = threadIdx.x;
  __shared__ float kb[C * FP];                  // k_bar [i][a] f32
  __shared__ float vb[C * FP];                  // v     [i][c] f32
  __shared__ alignas(16) short kT[D * PITCH];   // [a][i] bf16
  __shared__ alignas(16) short vT[D * PITCH];   // [c][i] bf16

  const float* kp = k + (size_t)(h * S + ch * C) * D;
  const float* vp = v + (size_t)(h * S + ch * C) * D;
  const float* ck = coef_k + h * S + ch * C;

#pragma unroll
  for (int r = 0; r < 4; ++r) {
    int o = 1024 * r + 4 * t;
    int i = o >> 6, d = o & 63;
    F4 kv = *reinterpret_cast<const F4*>(kp + o);
    F4 vv = *reinterpret_cast<const F4*>(vp + o);
    float c = ck[i];
#pragma unroll
    for (int u = 0; u < 4; ++u) kv.v[u] *= c;
    *reinterpret_cast<F4*>(&kb[i * FP + d]) = kv;
    *reinterpret_cast<F4*>(&vb[i * FP + d]) = vv;
  }
  __syncthreads();

  // transpose to bf16: thread owns column (t&63), i-range 16*(t>>6)
  {
    const int col = t & 63, i0 = 16 * (t >> 6);
    bf16x8 wk[2], wv[2];
#pragma unroll
    for (int g = 0; g < 2; ++g)
#pragma unroll
      for (int u = 0; u < 8; ++u) {
        wk[g][u] = rne_bf16(kb[(i0 + 8 * g + u) * FP + col]);
        wv[g][u] = rne_bf16(vb[(i0 + 8 * g + u) * FP + col]);
      }
    *reinterpret_cast<bf16x8*>(&kT[col * PITCH + i0]) = wk[0];
    *reinterpret_cast<bf16x8*>(&kT[col * PITCH + i0 + 8]) = wk[1];
    *reinterpret_cast<bf16x8*>(&vT[col * PITCH + i0]) = wv[0];
    *reinterpret_cast<bf16x8*>(&vT[col * PITCH + i0 + 8]) = wv[1];
  }
  __syncthreads();

  // MFMA: wave w owns output rows c = 16w..16w+15; n-tiles over a
  const int lane = t & 63, w = t >> 6;
  const int arow = lane & 15, kg = lane >> 4;
  const int abase = (16 * w + arow) * PITCH + 8 * kg;
  bf16x8 a0 = *reinterpret_cast<const bf16x8*>(&vT[abase]);
  bf16x8 a1 = *reinterpret_cast<const bf16x8*>(&vT[abase + 32]);
  float* dst = wsKV + (size_t)(h * NC + ch) * (D * D);
#pragma unroll
  for (int n = 0; n < 4; ++n) {
    const int bb = (16 * n + arow) * PITCH + 8 * kg;
    bf16x8 b0 = *reinterpret_cast<const bf16x8*>(&kT[bb]);
    bf16x8 b1 = *reinterpret_cast<const bf16x8*>(&kT[bb + 32]);
    f32x4 z = {0.f, 0.f, 0.f, 0.f};
    z = __builtin_amdgcn_mfma_f32_16x16x32_bf16(a0, b0, z, 0, 0, 0);
    z = __builtin_amdgcn_mfma_f32_16x16x32_bf16(a1, b1, z, 0, 0, 0);
#pragma unroll
    for (int r = 0; r < 4; ++r)
      dst[(16 * w + 4 * kg + r) * D + 16 * n + arow] = z[r];
  }
}

// ---------------------------------------------------------------------------
// Kernel 2: exclusive prefix scan across chunks (per head), writing each
// prefix back IN PLACE as packed {bf16 hi, bf16 lo}. 16-deep load batching.
// ---------------------------------------------------------------------------
__global__ __launch_bounds__(128) void k_scan(float* __restrict__ wsKV) {
  const int seg = blockIdx.x, h = blockIdx.y, t = threadIdx.x;
  const int e0 = seg * 128 + t;
  unsigned* wp = reinterpret_cast<unsigned*>(wsKV);
  float run = 0.f;
  for (int base = 0; base < NC; base += 16) {
    float x[16];
#pragma unroll
    for (int u = 0; u < 16; ++u)
      x[u] = wsKV[(size_t)(h * NC + base + u) * (D * D) + e0];
#pragma unroll
    for (int u = 0; u < 16; ++u) {
      short hi = rne_bf16(run);
      short lo = rne_bf16(run - bf16_to_f(hi));
      wp[(size_t)(h * NC + base + u) * (D * D) + e0] =
          (((unsigned)(unsigned short)lo) << 16) | (unsigned)(unsigned short)hi;
      run += x[u];
    }
  }
}

// ---------------------------------------------------------------------------
// Kernel 3: per-chunk output via MFMA 16x16x32 bf16.
//   A = tril(q_bar K_bar^T);  O = q_bar*(S0hi+S0lo) + A*V;  rmsnorm(O).
// ---------------------------------------------------------------------------
__global__ __launch_bounds__(256) void k_chunk_out(
    const float* __restrict__ q, const float* __restrict__ k,
    const float* __restrict__ v,
    const float* __restrict__ coef_q, const float* __restrict__ coef_k,
    const float* __restrict__ mask_normer,
    const float* __restrict__ wsKV, float* __restrict__ out) {
  const int ch = blockIdx.x, h = blockIdx.y, t = threadIdx.x;
  __shared__ alignas(16) short qb[C * PITCH];    // q_bar  [i][a]
  __shared__ alignas(16) short kbf[C * PITCH];   // k_bar  [j][a]
  __shared__ alignas(16) short s0h[D * PITCH];   // S0 hi  [c][a]
  __shared__ alignas(16) short s0l[D * PITCH];   // S0 lo  [c][a]
  __shared__ alignas(16) short vT[D * PITCH];    // v^T    [c][j]
  __shared__ alignas(16) short Ab[C * PITCH];    // A      [i][j]
  __shared__ float vb[C * FP];                   // v f32  [j][c]

  const size_t base = (size_t)(h * S + ch * C) * D;
  const float* qp = q + base;
  const float* kp = k + base;
  const float* vp = v + base;
  const float* cq = coef_q + h * S + ch * C;
  const float* ck = coef_k + h * S + ch * C;
  const float* mn = mask_normer + h * S + ch * C;
  const unsigned* s0p =
      reinterpret_cast<const unsigned*>(wsKV) + (size_t)(h * NC + ch) * (D * D);

  // ---- staging: thread t handles 16 contiguous elements (row t>>2, col16 t&3)
  {
    const int i = t >> 2, c0 = (t & 3) * 16;
    const float sq = cq[i] / mn[i];
    const float sk = ck[i];
    bf16x8 wq[2], wk[2], wh[2], wl[2];
#pragma unroll
    for (int g = 0; g < 2; ++g) {
#pragma unroll
      for (int u0 = 0; u0 < 8; u0 += 4) {
        F4 qv = *reinterpret_cast<const F4*>(qp + i * D + c0 + 8 * g + u0);
        F4 kv = *reinterpret_cast<const F4*>(kp + i * D + c0 + 8 * g + u0);
#pragma unroll
        for (int u = 0; u < 4; ++u) {
          wq[g][u0 + u] = rne_bf16(qv.v[u] * sq);
          wk[g][u0 + u] = rne_bf16(kv.v[u] * sk);
        }
      }
      uint4v p = *reinterpret_cast<const uint4v*>(s0p + i * D + c0 + 8 * g);
      uint4v p2 = *reinterpret_cast<const uint4v*>(s0p + i * D + c0 + 8 * g + 4);
#pragma unroll
      for (int u = 0; u < 4; ++u) {
        wh[g][u] = (short)(p[u] & 0xffffu);
        wl[g][u] = (short)(p[u] >> 16);
        wh[g][u + 4] = (short)(p2[u] & 0xffffu);
        wl[g][u + 4] = (short)(p2[u] >> 16);
      }
      // v f32 staging (row-major)
      F4 v0 = *reinterpret_cast<const F4*>(vp + i * D + c0 + 8 * g);
      F4 v1 = *reinterpret_cast<const F4*>(vp + i * D + c0 + 8 * g + 4);
      *reinterpret_cast<F4*>(&vb[i * FP + c0 + 8 * g]) = v0;
      *reinterpret_cast<F4*>(&vb[i * FP + c0 + 8 * g + 4]) = v1;
    }
#pragma unroll
    for (int g = 0; g < 2; ++g) {
      *reinterpret_cast<bf16x8*>(&qb[i * PITCH + c0 + 8 * g]) = wq[g];
      *reinterpret_cast<bf16x8*>(&kbf[i * PITCH + c0 + 8 * g]) = wk[g];
      *reinterpret_cast<bf16x8*>(&s0h[i * PITCH + c0 + 8 * g]) = wh[g];
      *reinterpret_cast<bf16x8*>(&s0l[i * PITCH + c0 + 8 * g]) = wl[g];
    }
  }
  __syncthreads();

  // ---- vT build from LDS: thread owns column (t&63), j-range 16*(t>>6)
  {
    const int col = t & 63, j0 = 16 * (t >> 6);
    bf16x8 wv[2];
#pragma unroll
    for (int g = 0; g < 2; ++g)
#pragma unroll
      for (int u = 0; u < 8; ++u)
        wv[g][u] = rne_bf16(vb[(j0 + 8 * g + u) * FP + col]);
    *reinterpret_cast<bf16x8*>(&vT[col * PITCH + j0]) = wv[0];
    *reinterpret_cast<bf16x8*>(&vT[col * PITCH + j0 + 8]) = wv[1];
  }

  const int lane = t & 63, w = t >> 6;
  const int arow = lane & 15, kg = lane >> 4;
  const int rbase = (16 * w + arow) * PITCH + 8 * kg;

  // q A-fragments (reused across all stages)
  bf16x8 qa0 = *reinterpret_cast<const bf16x8*>(&qb[rbase]);
  bf16x8 qa1 = *reinterpret_cast<const bf16x8*>(&qb[rbase + 32]);

  // ---- A-stage: wave w computes rows 16w..16w+15, all 4 col-tiles
  {
    f32x4 accA[4];
#pragma unroll
    for (int n = 0; n < 4; ++n) {
      const int bb = (16 * n + arow) * PITCH + 8 * kg;
      bf16x8 b0 = *reinterpret_cast<const bf16x8*>(&kbf[bb]);
      bf16x8 b1 = *reinterpret_cast<const bf16x8*>(&kbf[bb + 32]);
      f32x4 z = {0.f, 0.f, 0.f, 0.f};
      z = __builtin_amdgcn_mfma_f32_16x16x32_bf16(qa0, b0, z, 0, 0, 0);
      z = __builtin_amdgcn_mfma_f32_16x16x32_bf16(qa1, b1, z, 0, 0, 0);
      accA[n] = z;
    }
#pragma unroll
    for (int n = 0; n < 4; ++n)
#pragma unroll
      for (int r = 0; r < 4; ++r) {
        int i = 4 * kg + r;
        int j = 16 * n + arow;
        float x = (j <= 16 * w + i) ? accA[n][r] : 0.f;
        Ab[(16 * w + i) * PITCH + j] = rne_bf16(x);
      }
  }
  __syncthreads();   // vT + Ab visible

  // ---- O-stage
  bf16x8 aa0 = *reinterpret_cast<const bf16x8*>(&Ab[rbase]);
  bf16x8 aa1 = *reinterpret_cast<const bf16x8*>(&Ab[rbase + 32]);
  f32x4 accO[4];
#pragma unroll
  for (int n = 0; n < 4; ++n) {
    const int bb = (16 * n + arow) * PITCH + 8 * kg;
    bf16x8 h0 = *reinterpret_cast<const bf16x8*>(&s0h[bb]);
    bf16x8 h1 = *reinterpret_cast<const bf16x8*>(&s0h[bb + 32]);
    bf16x8 l0 = *reinterpret_cast<const bf16x8*>(&s0l[bb]);
    bf16x8 l1 = *reinterpret_cast<const bf16x8*>(&s0l[bb + 32]);
    bf16x8 v0 = *reinterpret_cast<const bf16x8*>(&vT[bb]);
    bf16x8 v1 = *reinterpret_cast<const bf16x8*>(&vT[bb + 32]);
    f32x4 z = {0.f, 0.f, 0.f, 0.f};
    z = __builtin_amdgcn_mfma_f32_16x16x32_bf16(qa0, h0, z, 0, 0, 0);
    z = __builtin_amdgcn_mfma_f32_16x16x32_bf16(qa1, h1, z, 0, 0, 0);
    z = __builtin_amdgcn_mfma_f32_16x16x32_bf16(qa0, l0, z, 0, 0, 0);
    z = __builtin_amdgcn_mfma_f32_16x16x32_bf16(qa1, l1, z, 0, 0, 0);
    z = __builtin_amdgcn_mfma_f32_16x16x32_bf16(aa0, v0, z, 0, 0, 0);
    z = __builtin_amdgcn_mfma_f32_16x16x32_bf16(aa1, v1, z, 0, 0, 0);
    accO[n] = z;
  }

  // ---- epilogue: rmsnorm per row (row lives in one quarter-wave)
  float* op = out + base;
#pragma unroll
  for (int r = 0; r < 4; ++r) {
    const int i = 16 * w + 4 * kg + r;
    float ss = 0.f;
#pragma unroll
    for (int n = 0; n < 4; ++n) ss += accO[n][r] * accO[n][r];
#pragma unroll
    for (int off = 1; off < 16; off <<= 1) ss += __shfl_xor(ss, off);
    const float sc = rsqrtf(ss * (1.0f / D) + 1e-6f);
#pragma unroll
    for (int n = 0; n < 4; ++n)
      op[(size_t)i * D + 16 * n + arow] = accO[n][r] * sc;
  }
}

// ---------------------------------------------------------------------------
extern "C" void kernel_launch(void* const* d_in, const int* in_sizes, int n_in,
                              void* d_out, int out_size, void* d_ws, size_t ws_size,
                              hipStream_t stream) {
  (void)in_sizes; (void)n_in; (void)out_size; (void)ws_size;
  const float* q  = (const float*)d_in[0];
  const float* k  = (const float*)d_in[1];
  const float* v  = (const float*)d_in[2];
  const float* cq = (const float*)d_in[3];
  const float* ck = (const float*)d_in[4];
  const float* mn = (const float*)d_in[5];
  float* out = (float*)d_out;

  float* wsKV = (float*)d_ws;   // H*NC*D*D floats (8 MiB), packed in place by k_scan

  k_chunk_sums<<<dim3(NC, H), dim3(256), 0, stream>>>(k, v, ck, wsKV);
  k_scan<<<dim3(32, H), dim3(128), 0, stream>>>(wsKV);
  k_chunk_out<<<dim3(NC, H), dim3(256), 0, stream>>>(q, k, v, cq, ck, mn, wsKV, out);
}